// Round 5
// baseline (130.802 us; speedup 1.0000x reference)
//
#include <hip/hip_runtime.h>

#define B_ 2
#define L_ 2048
#define H_ 8
#define D_ 64
#define W_ 16        // LOCAL_WINDOW/2
#define SP_ 65       // STRIDE+1
#define NC_ 128      // level-1 chunks per (b,h), chunk = 16 rows
#define NL2_ 8       // level-2 chunks per (b,h), chunk = 256 rows

// ---------------- Kernel 1: level-1 chunk sums of values (chunk = 16 rows) --
__global__ void chunk_sums_k(const float* __restrict__ v, float* __restrict__ csum1) {
    int blk = blockIdx.x;
    int c  = blk % NC_;
    int bh = blk / NC_;
    int h = bh % H_;
    int b = bh / H_;
    int d = threadIdx.x;
    float s = 0.f;
    int l0 = c * 16;
    #pragma unroll
    for (int l = 0; l < 16; ++l)
        s += v[((b * L_ + l0 + l) * H_ + h) * D_ + d];
    csum1[(bh * NC_ + c) * D_ + d] = s;
}

// ---------------- Kernel 2: level-2 sums (chunk = 256 rows = 16 level-1) ----
__global__ void l2_sums_k(const float* __restrict__ csum1, float* __restrict__ csum2) {
    int blk = blockIdx.x;
    int c2 = blk % NL2_;
    int bh = blk / NL2_;
    int d  = threadIdx.x;
    float s = 0.f;
    #pragma unroll
    for (int cc = 0; cc < 16; ++cc)
        s += csum1[(bh * NC_ + c2 * 16 + cc) * D_ + d];
    csum2[(bh * NL2_ + c2) * D_ + d] = s;
}

// ---------------- Kernel 3: TWO waves per query row ------------------------
// Block = 256 thr = 4 waves = 2 rows (waves {0,1} -> row A, {2,3} -> row B).
// Each wave = 8 groups x 8 lanes; lane owns dims [8*sub, 8*sub+8).
// Row's 16 column-slots = grp + 8*half (half = wave's index within the row);
// slot s takes every 16th selected column -> ~2.7 iterations per wave.
// Halves combine via LDS (64 floats + z per wave) after one barrier.
__global__ __launch_bounds__(256) void dozer_k(const float* __restrict__ q,
                                               const float* __restrict__ k,
                                               const float* __restrict__ v,
                                               const float* __restrict__ csum1,
                                               const float* __restrict__ csum2,
                                               float* __restrict__ out) {
    __shared__ float sm[4][72];   // per-wave reduced numerator (64 used, pad)
    __shared__ float zs[4];       // per-wave reduced z

    int lane = threadIdx.x & 63;
    int wib  = threadIdx.x >> 6;      // 0..3
    int grp  = lane >> 3;             // 0..7
    int sub  = lane & 7;              // owns dims 8*sub..8*sub+7
    int half = wib & 1;
    int slot = grp + 8 * half;        // 0..15

    int R  = 2 * blockIdx.x + (wib >> 1);   // flat (bh, i) row id
    int i  = R & (L_ - 1);
    int bh = R >> 11;                 // L_ = 2048
    int hh = bh & (H_ - 1);
    int b  = bh >> 3;

    const int rs = H_ * D_;           // 512 floats between consecutive seq rows
    const float* qp = q + ((size_t)(b * L_ + i) * H_ + hh) * D_ + 8 * sub;
    float4 q0 = *(const float4*)qp;
    float4 q1 = *(const float4*)(qp + 4);

    const float* kbase = k + ((size_t)b * L_ * H_ + hh) * D_ + 8 * sub;
    const float* vbase = v + ((size_t)b * L_ * H_ + hh) * D_ + 8 * sub;

    float4 n0 = make_float4(0.f, 0.f, 0.f, 0.f), n1 = n0;
    float z = 0.f;

    int c1 = i >> 4;
    int c2 = i >> 8;
    int pstart = c1 << 4;

    // ---- local window: o = slot, slot+16 (while o <= min(i,16))
    int omax = (i < W_) ? i : W_;
    for (int o = slot; o <= omax; o += 16) {
        int j = i - o;
        const float* kr = kbase + (size_t)j * rs;
        const float* vr = vbase + (size_t)j * rs;
        float4 k0 = *(const float4*)kr;
        float4 k1 = *(const float4*)(kr + 4);
        float4 v0 = *(const float4*)vr;
        float4 v1 = *(const float4*)(vr + 4);
        float p = q0.x*k0.x + q0.y*k0.y + q0.z*k0.z + q0.w*k0.w
                + q1.x*k1.x + q1.y*k1.y + q1.z*k1.z + q1.w*k1.w;
        p += __shfl_xor(p, 1, 64);
        p += __shfl_xor(p, 2, 64);
        p += __shfl_xor(p, 4, 64);
        float we = __expf(0.125f * p) - 1.f;
        z += we;
        float wv = we + ((j >= pstart) ? 1.f : 0.f);   // fold partial prefix row
        n0.x += wv*v0.x; n0.y += wv*v0.y; n0.z += wv*v0.z; n0.w += wv*v0.w;
        n1.x += wv*v1.x; n1.y += wv*v1.y; n1.z += wv*v1.z; n1.w += wv*v1.w;
    }

    // ---- strided: t = 1+slot, +16 (while t <= i/65)
    int tmax = i / SP_;
    for (int t = 1 + slot; t <= tmax; t += 16) {
        int j = i - SP_ * t;
        const float* kr = kbase + (size_t)j * rs;
        const float* vr = vbase + (size_t)j * rs;
        float4 k0 = *(const float4*)kr;
        float4 k1 = *(const float4*)(kr + 4);
        float4 v0 = *(const float4*)vr;
        float4 v1 = *(const float4*)(vr + 4);
        float p = q0.x*k0.x + q0.y*k0.y + q0.z*k0.z + q0.w*k0.w
                + q1.x*k1.x + q1.y*k1.y + q1.z*k1.z + q1.w*k1.w;
        p += __shfl_xor(p, 1, 64);
        p += __shfl_xor(p, 2, 64);
        p += __shfl_xor(p, 4, 64);
        float we = __expf(0.125f * p) - 1.f;
        z += we;
        n0.x += we*v0.x; n0.y += we*v0.y; n0.z += we*v0.z; n0.w += we*v0.w;
        n1.x += we*v1.x; n1.y += we*v1.y; n1.z += we*v1.z; n1.w += we*v1.w;
    }

    // ---- prefix chunks: level-2 (cc < c2 <= 7), then level-1 within
    const float* cs2 = csum2 + (size_t)bh * NL2_ * D_ + 8 * sub;
    for (int cc = slot; cc < c2; cc += 16) {
        float4 a = *(const float4*)(cs2 + (size_t)cc * D_);
        float4 bb = *(const float4*)(cs2 + (size_t)cc * D_ + 4);
        n0.x += a.x;  n0.y += a.y;  n0.z += a.z;  n0.w += a.w;
        n1.x += bb.x; n1.y += bb.y; n1.z += bb.z; n1.w += bb.w;
    }
    const float* cs1 = csum1 + (size_t)bh * NC_ * D_ + 8 * sub;
    for (int cc = (c2 << 4) + slot; cc < c1; cc += 16) {
        float4 a = *(const float4*)(cs1 + (size_t)cc * D_);
        float4 bb = *(const float4*)(cs1 + (size_t)cc * D_ + 4);
        n0.x += a.x;  n0.y += a.y;  n0.z += a.z;  n0.w += a.w;
        n1.x += bb.x; n1.y += bb.y; n1.z += bb.z; n1.w += bb.w;
    }

    // ---- in-wave cross-group reduce (xor 8,16,32) over 9 values
    #pragma unroll
    for (int m = 8; m <= 32; m <<= 1) {
        n0.x += __shfl_xor(n0.x, m, 64); n0.y += __shfl_xor(n0.y, m, 64);
        n0.z += __shfl_xor(n0.z, m, 64); n0.w += __shfl_xor(n0.w, m, 64);
        n1.x += __shfl_xor(n1.x, m, 64); n1.y += __shfl_xor(n1.y, m, 64);
        n1.z += __shfl_xor(n1.z, m, 64); n1.w += __shfl_xor(n1.w, m, 64);
        z    += __shfl_xor(z, m, 64);
    }

    if (grp == 0) {                   // lanes 0..7: sub = lane
        *(float4*)&sm[wib][sub * 8]     = n0;
        *(float4*)&sm[wib][sub * 8 + 4] = n1;
        if (sub == 0) zs[wib] = z;
    }
    __syncthreads();

    // ---- combine halves: wave 0 -> row A, wave 2 -> row B; lane d = dim
    if (half == 0) {
        float val = sm[wib][lane] + sm[wib + 1][lane];
        float inv = 1.f / (zs[wib] + zs[wib + 1] + (float)(i + 1));
        out[((size_t)(b * L_ + i) * H_ + hh) * D_ + lane] = val * inv;
    }
}

extern "C" void kernel_launch(void* const* d_in, const int* in_sizes, int n_in,
                              void* d_out, int out_size, void* d_ws, size_t ws_size,
                              hipStream_t stream) {
    const float* q = (const float*)d_in[0];
    const float* k = (const float*)d_in[1];
    const float* v = (const float*)d_in[2];
    // d_in[3] = attn_mask: deterministic causal — not read.
    float* out = (float*)d_out;

    float* csum1 = (float*)d_ws;                         // B*H*NC*D  = 131072 floats
    float* csum2 = csum1 + (size_t)B_ * H_ * NC_ * D_;   // B*H*NL2*D = 8192 floats

    chunk_sums_k<<<B_ * H_ * NC_, 64, 0, stream>>>(v, csum1);
    l2_sums_k   <<<B_ * H_ * NL2_, 64, 0, stream>>>(csum1, csum2);

    int blocks = B_ * H_ * L_ / 2;    // 16384 blocks, 2 rows (4 waves) each
    dozer_k<<<blocks, 256, 0, stream>>>(q, k, v, csum1, csum2, out);
}

// Round 6
// 118.142 us; speedup vs baseline: 1.1072x; 1.1072x over previous
//
#include <hip/hip_runtime.h>
#include <hip/hip_bf16.h>

#define B_ 2
#define L_ 2048
#define H_ 8
#define D_ 64
#define SP_ 65       // STRIDE+1
#define NC_ 128      // level-1 chunks (16 rows each)
#define NL2_ 8       // level-2 chunks (256 rows each)
#define RS_ 512      // H_*D_ floats between consecutive seq rows

typedef __attribute__((ext_vector_type(8))) short bf16x8;
typedef __attribute__((ext_vector_type(16))) float f32x16;

static __device__ inline short f2bf(float x) {
    return __builtin_bit_cast(short, __float2bfloat16(x));
}

static __device__ inline bf16x8 ld8_bf16(const float* __restrict__ p) {
    float4 a = *(const float4*)p;
    float4 b = *(const float4*)(p + 4);
    bf16x8 r;
    r[0]=f2bf(a.x); r[1]=f2bf(a.y); r[2]=f2bf(a.z); r[3]=f2bf(a.w);
    r[4]=f2bf(b.x); r[5]=f2bf(b.y); r[6]=f2bf(b.z); r[7]=f2bf(b.w);
    return r;
}

// ---------------- level-1 chunk sums of V (chunk = 16 rows) -----------------
__global__ void chunk_sums_k(const float* __restrict__ v, float* __restrict__ csum1) {
    int blk = blockIdx.x;
    int c  = blk % NC_;
    int bh = blk / NC_;
    int h = bh % H_, b = bh / H_;
    int d = threadIdx.x;
    float s = 0.f;
    int l0 = c * 16;
    #pragma unroll
    for (int l = 0; l < 16; ++l)
        s += v[((size_t)(b * L_ + l0 + l) * H_ + h) * D_ + d];
    csum1[(bh * NC_ + c) * D_ + d] = s;
}

// ---------------- level-2 sums (chunk = 256 rows) ---------------------------
__global__ void l2_sums_k(const float* __restrict__ csum1, float* __restrict__ csum2) {
    int blk = blockIdx.x;
    int c2 = blk % NL2_;
    int bh = blk / NL2_;
    int d  = threadIdx.x;
    float s = 0.f;
    #pragma unroll
    for (int cc = 0; cc < 16; ++cc)
        s += csum1[(bh * NC_ + c2 * 16 + cc) * D_ + d];
    csum2[(bh * NL2_ + c2) * D_ + d] = s;
}

// ---------------- Kernel A: local window + prefix, MFMA, 32-row tiles -------
// One wave per tile. Rows i = T+m (m=lane&31 in A frags). Key cols: band
// [T-16, T+48) as two 32-col tiles. Writes partialA[row][dim] (numer incl.
// prefix) and zA[row] (local z) to workspace.
__global__ __launch_bounds__(64) void local_k(const float* __restrict__ q,
                                              const float* __restrict__ kk,
                                              const float* __restrict__ v,
                                              const float* __restrict__ csum1,
                                              const float* __restrict__ csum2,
                                              float* __restrict__ pA,
                                              float* __restrict__ zA) {
    __shared__ float Pw[32][68];   // W matrix 32x64, row pad to 68 (16B-mult)

    int lane = threadIdx.x;
    int half = lane >> 5, ln = lane & 31;
    int bh = blockIdx.x >> 6;          // 64 tiles per bh
    int T  = (blockIdx.x & 63) << 5;
    int h = bh & 7, b = bh >> 3;

    const size_t base = (size_t)b * L_ * RS_ + (size_t)h * D_;

    // ---- QK^T: A frags from Q row T+ln; B frags from K rows (band)
    const float* qrow = q + base + (size_t)(T + ln) * RS_;
    bf16x8 aq[4];
    #pragma unroll
    for (int kb = 0; kb < 4; ++kb) aq[kb] = ld8_bf16(qrow + kb * 16 + half * 8);

    int j0 = T - 16 + ln; j0 = j0 < 0 ? 0 : j0;
    int j1 = T + 16 + ln; j1 = j1 > L_ - 1 ? L_ - 1 : j1;
    const float* kr0 = kk + base + (size_t)j0 * RS_;
    const float* kr1 = kk + base + (size_t)j1 * RS_;
    f32x16 acc0 = {}; f32x16 acc1 = {};
    #pragma unroll
    for (int kb = 0; kb < 4; ++kb) {
        bf16x8 b0 = ld8_bf16(kr0 + kb * 16 + half * 8);
        bf16x8 b1 = ld8_bf16(kr1 + kb * 16 + half * 8);
        acc0 = __builtin_amdgcn_mfma_f32_32x32x16_bf16(aq[kb], b0, acc0, 0, 0, 0);
        acc1 = __builtin_amdgcn_mfma_f32_32x32x16_bf16(aq[kb], b1, acc1, 0, 0, 0);
    }

    // ---- weights (exp-1 masked + "+1" prefix-fold) into LDS
    // tile0 col n=ln -> j = T-16+n, o = i-j = m-n+16 in [0,16] <=> m<=n<=m+16
    // tile1 col n=ln -> j = T+16+n, o = m-n-16 in [0,16] <=> n<=m-16
    #pragma unroll
    for (int r = 0; r < 16; ++r) {
        int m = (r & 3) + 8 * (r >> 2) + 4 * half;
        bool a0 = (ln >= m) && (ln <= m + 16) && (T - 16 + ln >= 0);
        float w0 = a0 ? (__expf(0.125f * acc0[r]) - 1.f) : 0.f;
        if ((m < 16) && (ln >= 16) && (ln <= m + 16)) w0 += 1.f;  // +1: j in [T, i]
        bool a1 = (ln <= m - 16);
        float w1 = a1 ? (__expf(0.125f * acc1[r]) - 1.f) : 0.f;
        if ((m >= 16) && (ln <= m - 16)) w1 += 1.f;               // +1: j in [T+16, i]
        Pw[m][ln]      = w0;
        Pw[m][32 + ln] = w1;
    }
    __syncthreads();

    // ---- PV (+ ones column for row sums)
    f32x16 p0 = {}; f32x16 p1 = {}; f32x16 po = {};
    bf16x8 ones = {};
    if (ln == 0) { short o = f2bf(1.f); for (int t = 0; t < 8; ++t) ones[t] = o; }
    #pragma unroll
    for (int kb = 0; kb < 4; ++kb) {
        int k0 = kb * 16 + half * 8;
        const float* pr = &Pw[ln][k0];
        float4 x = *(const float4*)pr;
        float4 y = *(const float4*)(pr + 4);
        bf16x8 ap;
        ap[0]=f2bf(x.x); ap[1]=f2bf(x.y); ap[2]=f2bf(x.z); ap[3]=f2bf(x.w);
        ap[4]=f2bf(y.x); ap[5]=f2bf(y.y); ap[6]=f2bf(y.z); ap[7]=f2bf(y.w);
        bf16x8 bv0, bv1;
        #pragma unroll
        for (int jj = 0; jj < 8; ++jj) {
            int c = k0 + jj;
            int jr = T - 16 + c;
            jr = jr < 0 ? 0 : (jr > L_ - 1 ? L_ - 1 : jr);
            const float* vr = v + base + (size_t)jr * RS_;
            bv0[jj] = f2bf(vr[ln]);
            bv1[jj] = f2bf(vr[32 + ln]);
        }
        p0 = __builtin_amdgcn_mfma_f32_32x32x16_bf16(ap, bv0, p0, 0, 0, 0);
        p1 = __builtin_amdgcn_mfma_f32_32x32x16_bf16(ap, bv1, p1, 0, 0, 0);
        po = __builtin_amdgcn_mfma_f32_32x32x16_bf16(ap, ones, po, 0, 0, 0);
    }

    // ---- prefix walk (chunks below T, plus chunk T>>4 for upper half rows)
    int c2n = T >> 8;
    int c1a = (T >> 8) << 4, c1b = T >> 4;
    const float* cs2 = csum2 + (size_t)bh * NL2_ * D_;
    const float* cs1 = csum1 + (size_t)bh * NC_ * D_;
    float pr0 = 0.f, pr1 = 0.f;
    for (int cc = 0; cc < c2n; ++cc) {
        pr0 += cs2[cc * D_ + ln]; pr1 += cs2[cc * D_ + 32 + ln];
    }
    for (int cc = c1a; cc < c1b; ++cc) {
        pr0 += cs1[cc * D_ + ln]; pr1 += cs1[cc * D_ + 32 + ln];
    }
    float ch0 = cs1[c1b * D_ + ln], ch1 = cs1[c1b * D_ + 32 + ln];

    // ---- epilogue: partialA = PV + prefix; zA = rowsum - (#(+1) = (m&15)+1)
    float* pArow = pA + (size_t)bh * L_ * D_;
    float* zrow  = zA + (size_t)bh * L_;
    #pragma unroll
    for (int r = 0; r < 16; ++r) {
        int m = (r & 3) + 8 * (r >> 2) + 4 * half;
        int i = T + m;
        float e0 = pr0 + ((m & 16) ? ch0 : 0.f);
        float e1 = pr1 + ((m & 16) ? ch1 : 0.f);
        pArow[(size_t)i * D_ + ln]      = p0[r] + e0;
        pArow[(size_t)i * D_ + 32 + ln] = p1[r] + e1;
        if (ln == 0) zrow[i] = po[r] - (float)((m & 15) + 1);
    }
}

// ---------------- Kernel B: strided (residue classes mod 65), MFMA ----------
// One wave per (bh, residue r). Rows l = r + 65*s, s=0..31 (clamped); scores
// strictly lower-triangular in s. Adds partialA + prefix-z, divides, writes out.
__global__ __launch_bounds__(64) void strided_k(const float* __restrict__ q,
                                                const float* __restrict__ kk,
                                                const float* __restrict__ v,
                                                const float* __restrict__ pA,
                                                const float* __restrict__ zA,
                                                float* __restrict__ out) {
    __shared__ float Pw[32][36];

    int lane = threadIdx.x;
    int half = lane >> 5, ln = lane & 31;
    int bh = blockIdx.x / SP_;
    int r  = blockIdx.x % SP_;
    int h = bh & 7, b = bh >> 3;

    const size_t base = (size_t)b * L_ * RS_ + (size_t)h * D_;

    int lq = r + SP_ * ln;
    int lqc = lq > L_ - 1 ? L_ - 1 : lq;     // query row = key row set
    const float* qrow = q  + base + (size_t)lqc * RS_;
    const float* krow = kk + base + (size_t)lqc * RS_;

    f32x16 acc = {};
    #pragma unroll
    for (int kb = 0; kb < 4; ++kb) {
        bf16x8 a  = ld8_bf16(qrow + kb * 16 + half * 8);
        bf16x8 bb = ld8_bf16(krow + kb * 16 + half * 8);
        acc = __builtin_amdgcn_mfma_f32_32x32x16_bf16(a, bb, acc, 0, 0, 0);
    }

    #pragma unroll
    for (int rg = 0; rg < 16; ++rg) {
        int m = (rg & 3) + 8 * (rg >> 2) + 4 * half;      // query s-index
        bool act = (ln < m) && (r + SP_ * m < L_);        // strictly lower + valid
        float w = act ? (__expf(0.125f * acc[rg]) - 1.f) : 0.f;
        Pw[m][ln] = w;
    }
    __syncthreads();

    f32x16 p0 = {}; f32x16 p1 = {}; f32x16 po = {};
    bf16x8 ones = {};
    if (ln == 0) { short o = f2bf(1.f); for (int t = 0; t < 8; ++t) ones[t] = o; }
    #pragma unroll
    for (int kb = 0; kb < 2; ++kb) {
        int k0 = kb * 16 + half * 8;
        const float* pr = &Pw[ln][k0];
        float4 x = *(const float4*)pr;
        float4 y = *(const float4*)(pr + 4);
        bf16x8 ap;
        ap[0]=f2bf(x.x); ap[1]=f2bf(x.y); ap[2]=f2bf(x.z); ap[3]=f2bf(x.w);
        ap[4]=f2bf(y.x); ap[5]=f2bf(y.y); ap[6]=f2bf(y.z); ap[7]=f2bf(y.w);
        bf16x8 bv0, bv1;
        #pragma unroll
        for (int jj = 0; jj < 8; ++jj) {
            int s = k0 + jj;
            int lv = r + SP_ * s;
            lv = lv > L_ - 1 ? L_ - 1 : lv;
            const float* vr = v + base + (size_t)lv * RS_;
            bv0[jj] = f2bf(vr[ln]);
            bv1[jj] = f2bf(vr[32 + ln]);
        }
        p0 = __builtin_amdgcn_mfma_f32_32x32x16_bf16(ap, bv0, p0, 0, 0, 0);
        p1 = __builtin_amdgcn_mfma_f32_32x32x16_bf16(ap, bv1, p1, 0, 0, 0);
        po = __builtin_amdgcn_mfma_f32_32x32x16_bf16(ap, ones, po, 0, 0, 0);
    }

    const float* pArow = pA + (size_t)bh * L_ * D_;
    const float* zrow  = zA + (size_t)bh * L_;
    #pragma unroll
    for (int rg = 0; rg < 16; ++rg) {
        int m = (rg & 3) + 8 * (rg >> 2) + 4 * half;
        int l = r + SP_ * m;
        if (l < L_) {
            float zb = __shfl(po[rg], lane & 32, 64);   // broadcast col-0 row sum
            float inv = 1.f / (zrow[l] + zb + (float)(l + 1));
            float o0 = (p0[rg] + pArow[(size_t)l * D_ + ln]) * inv;
            float o1 = (p1[rg] + pArow[(size_t)l * D_ + 32 + ln]) * inv;
            out[base + (size_t)l * RS_ + ln]      = o0;
            out[base + (size_t)l * RS_ + 32 + ln] = o1;
        }
    }
}

extern "C" void kernel_launch(void* const* d_in, const int* in_sizes, int n_in,
                              void* d_out, int out_size, void* d_ws, size_t ws_size,
                              hipStream_t stream) {
    const float* q = (const float*)d_in[0];
    const float* k = (const float*)d_in[1];
    const float* v = (const float*)d_in[2];
    // d_in[3] = attn_mask: deterministic causal — not read.
    float* out = (float*)d_out;

    float* csum1 = (float*)d_ws;                          // 131072 f
    float* csum2 = csum1 + (size_t)B_ * H_ * NC_ * D_;    // 8192 f
    float* pA    = csum2 + (size_t)B_ * H_ * NL2_ * D_;   // 2097152 f
    float* zA    = pA    + (size_t)B_ * H_ * L_ * D_;     // 32768 f

    chunk_sums_k<<<B_ * H_ * NC_, 64, 0, stream>>>(v, csum1);
    l2_sums_k   <<<B_ * H_ * NL2_, 64, 0, stream>>>(csum1, csum2);

    local_k  <<<B_ * H_ * (L_ / 32), 64, 0, stream>>>(q, k, v, csum1, csum2, pA, zA);
    strided_k<<<B_ * H_ * SP_,       64, 0, stream>>>(q, k, v, pA, zA, out);
}

// Round 9
// 115.833 us; speedup vs baseline: 1.1292x; 1.0199x over previous
//
#include <hip/hip_runtime.h>
#include <hip/hip_bf16.h>

#define B_ 2
#define L_ 2048
#define H_ 8
#define D_ 64
#define SP_ 65       // STRIDE+1
#define NC_ 128      // level-1 chunks (16 rows each)
#define NL2_ 8       // level-2 chunks (256 rows each)
#define RS_ 512      // H_*D_ floats between consecutive seq rows

typedef __attribute__((ext_vector_type(8))) short bf16x8;
typedef __attribute__((ext_vector_type(16))) float f32x16;

static __device__ inline short f2bf(float x) {
    return __builtin_bit_cast(short, __float2bfloat16(x));
}

static __device__ inline bf16x8 ld8_bf16(const float* __restrict__ p) {
    float4 a = *(const float4*)p;
    float4 b = *(const float4*)(p + 4);
    bf16x8 r;
    r[0]=f2bf(a.x); r[1]=f2bf(a.y); r[2]=f2bf(a.z); r[3]=f2bf(a.w);
    r[4]=f2bf(b.x); r[5]=f2bf(b.y); r[6]=f2bf(b.z); r[7]=f2bf(b.w);
    return r;
}

static __device__ inline bf16x8 ones_frag() {
    bf16x8 r;
    short o = f2bf(1.f);
    #pragma unroll
    for (int t = 0; t < 8; ++t) r[t] = o;
    return r;
}

// ================= Kernel 1: strided-partial + csum1 + csum2 (all input-only)
// blk <  260 : strided residue waves (4 per block, 1040 units) -> pB, zB
// blk <  772 : csum1 (2048 units of 16-row sums)
// blk <  804 : csum2 direct from V (128 units of 256-row sums)
__global__ __launch_bounds__(256) void pre_strided_k(const float* __restrict__ q,
                                                     const float* __restrict__ kk,
                                                     const float* __restrict__ v,
                                                     float* __restrict__ csum1,
                                                     float* __restrict__ csum2,
                                                     float* __restrict__ pB,
                                                     float* __restrict__ zB) {
    __shared__ float Pw[4][32][36];
    int wib  = threadIdx.x >> 6;
    int lane = threadIdx.x & 63;
    int blk  = blockIdx.x;

    if (blk < 260) {
        // ---- strided residue classes mod 65: rows l = r + 65*s, s = 0..31
        int u  = blk * 4 + wib;          // 0..1039
        int bh = u / SP_;
        int r  = u % SP_;
        int h = bh & 7, b = bh >> 3;
        int half = lane >> 5, ln = lane & 31;
        const size_t base = (size_t)b * L_ * RS_ + (size_t)h * D_;

        // V prefetch (keys s = 0..31) before everything
        bf16x8 bv0[2], bv1[2];
        #pragma unroll
        for (int kb = 0; kb < 2; ++kb) {
            int k0 = kb * 16 + half * 8;
            #pragma unroll
            for (int jj = 0; jj < 8; ++jj) {
                int lv = r + SP_ * (k0 + jj);
                lv = lv > L_ - 1 ? L_ - 1 : lv;
                const float* vr = v + base + (size_t)lv * RS_;
                bv0[kb][jj] = f2bf(vr[ln]);
                bv1[kb][jj] = f2bf(vr[32 + ln]);
            }
        }

        int lq = r + SP_ * ln;
        int lqc = lq > L_ - 1 ? L_ - 1 : lq;
        const float* qrow = q  + base + (size_t)lqc * RS_;
        const float* krow = kk + base + (size_t)lqc * RS_;
        f32x16 acc = {};
        #pragma unroll
        for (int kb = 0; kb < 4; ++kb) {
            bf16x8 a  = ld8_bf16(qrow + kb * 16 + half * 8);
            bf16x8 bb = ld8_bf16(krow + kb * 16 + half * 8);
            acc = __builtin_amdgcn_mfma_f32_32x32x16_bf16(a, bb, acc, 0, 0, 0);
        }
        #pragma unroll
        for (int rg = 0; rg < 16; ++rg) {
            int m = (rg & 3) + 8 * (rg >> 2) + 4 * half;
            bool act = (ln < m) && (r + SP_ * m < L_);
            Pw[wib][m][ln] = act ? (__expf(0.125f * acc[rg]) - 1.f) : 0.f;
        }
        __syncthreads();

        f32x16 p0 = {}; f32x16 p1 = {}; f32x16 po = {};
        bf16x8 ones = ones_frag();
        #pragma unroll
        for (int kb = 0; kb < 2; ++kb) {
            int k0 = kb * 16 + half * 8;
            const float* pr = &Pw[wib][ln][k0];
            float4 x = *(const float4*)pr;
            float4 y = *(const float4*)(pr + 4);
            bf16x8 ap;
            ap[0]=f2bf(x.x); ap[1]=f2bf(x.y); ap[2]=f2bf(x.z); ap[3]=f2bf(x.w);
            ap[4]=f2bf(y.x); ap[5]=f2bf(y.y); ap[6]=f2bf(y.z); ap[7]=f2bf(y.w);
            p0 = __builtin_amdgcn_mfma_f32_32x32x16_bf16(ap, bv0[kb], p0, 0, 0, 0);
            p1 = __builtin_amdgcn_mfma_f32_32x32x16_bf16(ap, bv1[kb], p1, 0, 0, 0);
            po = __builtin_amdgcn_mfma_f32_32x32x16_bf16(ap, ones,    po, 0, 0, 0);
        }
        float* pBr = pB + (size_t)bh * L_ * D_;
        float* zBr = zB + (size_t)bh * L_;
        #pragma unroll
        for (int rg = 0; rg < 16; ++rg) {
            int m = (rg & 3) + 8 * (rg >> 2) + 4 * half;
            int l = r + SP_ * m;
            if (l < L_) {
                pBr[(size_t)l * D_ + ln]      = p0[rg];
                pBr[(size_t)l * D_ + 32 + ln] = p1[rg];
                if (ln == 0) zBr[l] = po[rg];
            }
        }
    } else if (blk < 772) {
        // ---- csum1: 16-row chunk sums
        int u = (blk - 260) * 4 + wib;   // 0..2047 == bh*128 + c
        int c = u & (NC_ - 1);
        int bh = u >> 7;
        int h = bh & 7, b = bh >> 3;
        const float* vb = v + (size_t)(b * L_ + c * 16) * RS_ + h * D_ + lane;
        float s = 0.f;
        #pragma unroll
        for (int l = 0; l < 16; ++l) s += vb[l * RS_];
        csum1[(size_t)u * D_ + lane] = s;
    } else {
        // ---- csum2 direct from V: 256-row sums (no csum1 dependency)
        int u = (blk - 772) * 4 + wib;   // 0..127 == bh*8 + c2
        int c2 = u & 7;
        int bh = u >> 3;
        int h = bh & 7, b = bh >> 3;
        const float* vb = v + (size_t)(b * L_ + c2 * 256) * RS_ + h * D_ + lane;
        float s0 = 0.f, s1 = 0.f, s2 = 0.f, s3 = 0.f;
        for (int l = 0; l < 256; l += 4) {
            s0 += vb[(l + 0) * RS_]; s1 += vb[(l + 1) * RS_];
            s2 += vb[(l + 2) * RS_]; s3 += vb[(l + 3) * RS_];
        }
        csum2[(size_t)u * D_ + lane] = (s0 + s1) + (s2 + s3);
    }
}

// ================= Kernel 2: local window + prefix + combine + divide ========
// 4 tiles (waves) per 256-thr block; tile = 32 query rows, key band [T-16,T+48).
// 1024 tiles total -> 256 blocks.
__global__ __launch_bounds__(256) void local_final_k(const float* __restrict__ q,
                                                     const float* __restrict__ kk,
                                                     const float* __restrict__ v,
                                                     const float* __restrict__ csum1,
                                                     const float* __restrict__ csum2,
                                                     const float* __restrict__ pB,
                                                     const float* __restrict__ zB,
                                                     float* __restrict__ out) {
    __shared__ float Pw[4][32][68];
    int wib  = threadIdx.x >> 6;
    int lane = threadIdx.x & 63;
    int half = lane >> 5, ln = lane & 31;
    int tile = blockIdx.x * 4 + wib;     // 0..1023
    int bh = tile >> 6;
    int T  = (tile & 63) << 5;
    int h = bh & 7, b = bh >> 3;
    const size_t base = (size_t)b * L_ * RS_ + (size_t)h * D_;

    // ---- V band prefetch (rows T-16 .. T+47), before everything
    bf16x8 bv0[4], bv1[4];
    #pragma unroll
    for (int kb = 0; kb < 4; ++kb) {
        int k0 = kb * 16 + half * 8;
        #pragma unroll
        for (int jj = 0; jj < 8; ++jj) {
            int jr = T - 16 + k0 + jj;
            jr = jr < 0 ? 0 : (jr > L_ - 1 ? L_ - 1 : jr);
            const float* vr = v + base + (size_t)jr * RS_;
            bv0[kb][jj] = f2bf(vr[ln]);
            bv1[kb][jj] = f2bf(vr[32 + ln]);
        }
    }

    // ---- QK^T over the band (two 32-col tiles)
    const float* qrow = q + base + (size_t)(T + ln) * RS_;
    bf16x8 aq[4];
    #pragma unroll
    for (int kb = 0; kb < 4; ++kb) aq[kb] = ld8_bf16(qrow + kb * 16 + half * 8);

    int j0 = T - 16 + ln; j0 = j0 < 0 ? 0 : j0;
    int j1 = T + 16 + ln; j1 = j1 > L_ - 1 ? L_ - 1 : j1;
    const float* kr0 = kk + base + (size_t)j0 * RS_;
    const float* kr1 = kk + base + (size_t)j1 * RS_;
    f32x16 acc0 = {}; f32x16 acc1 = {};
    #pragma unroll
    for (int kb = 0; kb < 4; ++kb) {
        bf16x8 b0 = ld8_bf16(kr0 + kb * 16 + half * 8);
        bf16x8 b1 = ld8_bf16(kr1 + kb * 16 + half * 8);
        acc0 = __builtin_amdgcn_mfma_f32_32x32x16_bf16(aq[kb], b0, acc0, 0, 0, 0);
        acc1 = __builtin_amdgcn_mfma_f32_32x32x16_bf16(aq[kb], b1, acc1, 0, 0, 0);
    }

    // ---- weights (exp-1 masked + "+1" prefix-fold) into LDS
    #pragma unroll
    for (int r = 0; r < 16; ++r) {
        int m = (r & 3) + 8 * (r >> 2) + 4 * half;
        bool a0 = (ln >= m) && (ln <= m + 16) && (T - 16 + ln >= 0);
        float w0 = a0 ? (__expf(0.125f * acc0[r]) - 1.f) : 0.f;
        if ((m < 16) && (ln >= 16) && (ln <= m + 16)) w0 += 1.f;
        bool a1 = (ln <= m - 16);
        float w1 = a1 ? (__expf(0.125f * acc1[r]) - 1.f) : 0.f;
        if ((m >= 16) && (ln <= m - 16)) w1 += 1.f;
        Pw[wib][m][ln]      = w0;
        Pw[wib][m][32 + ln] = w1;
    }
    __syncthreads();

    // ---- PV (+ ones column for row sums)
    f32x16 p0 = {}; f32x16 p1 = {}; f32x16 po = {};
    bf16x8 ones = ones_frag();
    #pragma unroll
    for (int kb = 0; kb < 4; ++kb) {
        int k0 = kb * 16 + half * 8;
        const float* pr = &Pw[wib][ln][k0];
        float4 x = *(const float4*)pr;
        float4 y = *(const float4*)(pr + 4);
        bf16x8 ap;
        ap[0]=f2bf(x.x); ap[1]=f2bf(x.y); ap[2]=f2bf(x.z); ap[3]=f2bf(x.w);
        ap[4]=f2bf(y.x); ap[5]=f2bf(y.y); ap[6]=f2bf(y.z); ap[7]=f2bf(y.w);
        p0 = __builtin_amdgcn_mfma_f32_32x32x16_bf16(ap, bv0[kb], p0, 0, 0, 0);
        p1 = __builtin_amdgcn_mfma_f32_32x32x16_bf16(ap, bv1[kb], p1, 0, 0, 0);
        po = __builtin_amdgcn_mfma_f32_32x32x16_bf16(ap, ones,    po, 0, 0, 0);
    }

    // ---- prefix walk (chunks below T; chunk [T,T+16) added for upper rows)
    int c2n = T >> 8;
    int c1a = (T >> 8) << 4, c1b = T >> 4;
    const float* cs2 = csum2 + (size_t)bh * NL2_ * D_;
    const float* cs1 = csum1 + (size_t)bh * NC_ * D_;
    float pr0 = 0.f, pr1 = 0.f;
    for (int cc = 0; cc < c2n; ++cc) {
        pr0 += cs2[cc * D_ + ln]; pr1 += cs2[cc * D_ + 32 + ln];
    }
    for (int cc = c1a; cc < c1b; ++cc) {
        pr0 += cs1[cc * D_ + ln]; pr1 += cs1[cc * D_ + 32 + ln];
    }
    float ch0 = cs1[c1b * D_ + ln], ch1 = cs1[c1b * D_ + 32 + ln];

    // ---- combine with strided partials, divide, write out
    const float* pBr = pB + (size_t)bh * L_ * D_;
    const float* zBr = zB + (size_t)bh * L_;
    #pragma unroll
    for (int r = 0; r < 16; ++r) {
        int m = (r & 3) + 8 * (r >> 2) + 4 * half;
        int i = T + m;
        float e0 = pr0 + ((m & 16) ? ch0 : 0.f);
        float e1 = pr1 + ((m & 16) ? ch1 : 0.f);
        float zloc = po[r] - (float)((m & 15) + 1);   // remove the +1-fold count
        float inv = 1.f / (zloc + zBr[i] + (float)(i + 1));
        out[base + (size_t)i * RS_ + ln]      = (p0[r] + e0 + pBr[(size_t)i * D_ + ln])      * inv;
        out[base + (size_t)i * RS_ + 32 + ln] = (p1[r] + e1 + pBr[(size_t)i * D_ + 32 + ln]) * inv;
    }
}

extern "C" void kernel_launch(void* const* d_in, const int* in_sizes, int n_in,
                              void* d_out, int out_size, void* d_ws, size_t ws_size,
                              hipStream_t stream) {
    const float* q = (const float*)d_in[0];
    const float* k = (const float*)d_in[1];
    const float* v = (const float*)d_in[2];
    // d_in[3] = attn_mask: deterministic causal — not read.
    float* out = (float*)d_out;

    float* csum1 = (float*)d_ws;                          // 131072 f
    float* csum2 = csum1 + (size_t)B_ * H_ * NC_ * D_;    // 8192 f
    float* pB    = csum2 + (size_t)B_ * H_ * NL2_ * D_;   // 2097152 f
    float* zB    = pB    + (size_t)B_ * H_ * L_ * D_;     // 32768 f

    // 260 strided + 512 csum1 + 32 csum2 blocks, all independent
    pre_strided_k<<<804, 256, 0, stream>>>(q, k, v, csum1, csum2, pB, zB);
    // local + prefix + combine + divide: 1024 tiles, 4 per block
    local_final_k<<<256, 256, 0, stream>>>(q, k, v, csum1, csum2, pB, zB, out);
}